// Round 4
// baseline (403.551 us; speedup 1.0000x reference)
//
#include <hip/hip_runtime.h>
#include <math.h>

#define NC 19
#define NB 8
#define HW (512 * 512)
#define PPB 2048            // pixels per block
#define TPB 256
#define NWAVE (TPB / 64)
#define BINS (NC * NC + NC) // 380: [i*NC + t] channel sums, then [361 + t] counts
#define BSTRIDE 384
#define FT 1024

typedef float v4f __attribute__((ext_vector_type(4)));
typedef int v4i __attribute__((ext_vector_type(4)));

// Workspace: Sg[NB][BINS] floats (12160 B), zeroed by hipMemsetAsync each call.

__global__ __launch_bounds__(TPB) void accum_kernel(const float* __restrict__ seg,
                                                    const int* __restrict__ tgt,
                                                    float* __restrict__ Sg) {
    // Per-wave bins: no cross-wave contention; within a wave, ds_add_f32
    // same-address collisions average ~3.4-way (64 lanes over 19 classes).
    __shared__ float wb[NWAVE * BSTRIDE];

    const int tid = threadIdx.x;
    const int wave = tid >> 6;
    const int chunk = blockIdx.x;  // 0..127
    const int b = blockIdx.y;

    for (int e = tid; e < NWAVE * BSTRIDE; e += TPB) wb[e] = 0.0f;
    __syncthreads();

    float* __restrict__ mywb = &wb[wave * BSTRIDE];

    const size_t pix = (size_t)chunk * PPB;
    const v4i* __restrict__ tgtv = (const v4i*)(tgt + (size_t)b * HW + pix);
    const float* __restrict__ segbase = seg + (size_t)b * NC * HW + pix;

    const int iters = PPB / 4 / TPB;  // 2
    #pragma unroll
    for (int it = 0; it < iters; ++it) {
        const int v = it * TPB + tid;
        const v4i t = tgtv[v];
        // Read the target ONCE per pixel; stream all 19 channel rows
        // (each row coalesced across lanes; nontemporal: read-once data).
        v4f z[NC];
        #pragma unroll
        for (int i = 0; i < NC; ++i)
            z[i] = __builtin_nontemporal_load((const v4f*)(segbase + (size_t)i * HW) + v);

        atomicAdd(&mywb[NC * NC + t.x], 1.0f);
        atomicAdd(&mywb[NC * NC + t.y], 1.0f);
        atomicAdd(&mywb[NC * NC + t.z], 1.0f);
        atomicAdd(&mywb[NC * NC + t.w], 1.0f);
        #pragma unroll
        for (int i = 0; i < NC; ++i) {
            atomicAdd(&mywb[i * NC + t.x], z[i].x);
            atomicAdd(&mywb[i * NC + t.y], z[i].y);
            atomicAdd(&mywb[i * NC + t.z], z[i].z);
            atomicAdd(&mywb[i * NC + t.w], z[i].w);
        }
    }
    __syncthreads();

    // Fold the 4 wave bins and flush to the global per-batch accumulator.
    for (int e = tid; e < BINS; e += TPB) {
        float s = 0.0f;
        #pragma unroll
        for (int w = 0; w < NWAVE; ++w) s += wb[w * BSTRIDE + e];
        atomicAdd(&Sg[(size_t)b * BINS + e], s);
    }
}

__global__ __launch_bounds__(FT) void finalize_kernel(const float* __restrict__ Sg,
                                                      float* __restrict__ out) {
    __shared__ float wsum[FT / 64];
    const int tid = threadIdx.x;
    const float eps = 2.220446049250313e-16f;  // np.spacing(1)
    float local = 0.0f;

    for (int idx = tid; idx < NB * NC * NC; idx += FT) {
        int b = idx / (NC * NC);
        int r = idx - b * NC * NC;
        int i = r / NC;
        int k = r - i * NC;
        const float* Sb = Sg + (size_t)b * BINS;
        float cnt_i = Sb[NC * NC + i];
        float cnt_k = Sb[NC * NC + k];
        float alpha = (cnt_i > 0.0f) ? Sb[i * NC + i] / cnt_i : 0.0f;
        float beta = (cnt_k > 0.0f) ? 1.0f - Sb[i * NC + k] / cnt_k : 0.0f;
        local += logf(0.5f * (alpha + beta + eps));
    }

    #pragma unroll
    for (int off = 32; off > 0; off >>= 1) local += __shfl_down(local, off);
    if ((tid & 63) == 0) wsum[tid >> 6] = local;
    __syncthreads();
    if (tid == 0) {
        float t = 0.0f;
        #pragma unroll
        for (int w = 0; w < FT / 64; ++w) t += wsum[w];
        out[0] = -0.5f * t / (float)NB;
    }
}

extern "C" void kernel_launch(void* const* d_in, const int* in_sizes, int n_in,
                              void* d_out, int out_size, void* d_ws, size_t ws_size,
                              hipStream_t stream) {
    const float* seg = (const float*)d_in[0];
    const int* tgt = (const int*)d_in[1];
    float* Sg = (float*)d_ws;

    hipMemsetAsync(Sg, 0, (size_t)NB * BINS * sizeof(float), stream);  // 12 KB

    dim3 grid(HW / PPB, NB);  // 128 x 8 = 1024 blocks = 4/CU
    accum_kernel<<<grid, TPB, 0, stream>>>(seg, tgt, Sg);
    finalize_kernel<<<1, FT, 0, stream>>>(Sg, (float*)d_out);
}

// Round 5
// 290.144 us; speedup vs baseline: 1.3909x; 1.3909x over previous
//
#include <hip/hip_runtime.h>
#include <math.h>

#define NC 19
#define NB 8
#define HW (512 * 512)
#define CHUNKS 64
#define NG 10   // channel pairs {0,1},{2,3},...,{16,17},{18,count}
#define TPB 256
#define FT 1024

typedef float v4f __attribute__((ext_vector_type(4)));
typedef float v2f __attribute__((ext_vector_type(2)));
typedef int v4i __attribute__((ext_vector_type(4)));

// Workspace: Sg[NB][NC][20] floats (12160 B, zeroed each call; col 0..18 =
// channel i sums for class t, col 19 = counts), then packed target (2 MB).

__global__ __launch_bounds__(TPB) void pack_kernel(const int* __restrict__ tgt,
                                                   int* __restrict__ pt) {
    // int32 labels (0..18) -> int8. 16 px/thread, fully coalesced.
    const size_t idx = (size_t)blockIdx.x * TPB + threadIdx.x;
    const v4i* tv = (const v4i*)tgt + idx * 4;
    int tmp[4];
    #pragma unroll
    for (int j = 0; j < 4; ++j) {
        v4i t = tv[j];
        tmp[j] = t.x | (t.y << 8) | (t.z << 16) | (t.w << 24);
    }
    v4i o; o.x = tmp[0]; o.y = tmp[1]; o.z = tmp[2]; o.w = tmp[3];
    ((v4i*)pt)[idx] = o;
}

__global__ __launch_bounds__(TPB) void accum_kernel(const float* __restrict__ seg,
                                                    const unsigned int* __restrict__ pt,
                                                    float* __restrict__ Sg) {
    // Per-thread PRIVATE bins (no atomics): 19 classes x float2 {ch c0, ch c1}.
    // One ds_read_b64 + packed add + ds_write_b64 per pixel covers both channels.
    // 152 B/thread -> 38.9 KB/block -> 4 blocks/CU.
    __shared__ __align__(8) float bins[TPB * NC * 2];

    const int tid = threadIdx.x;
    const int chunk = blockIdx.x;
    const int g = blockIdx.y;
    const int b = blockIdx.z;
    const bool last = (g == NG - 1);  // channel 18 + counts

    v2f* __restrict__ mybins = (v2f*)bins + tid * NC;
    #pragma unroll
    for (int t = 0; t < NC; ++t) mybins[t] = (v2f){0.0f, 0.0f};
    // Rows are thread-private until the fold: no barrier needed here.

    const int per_chunk = HW / CHUNKS;  // 4096 pixels
    const size_t pix = (size_t)chunk * per_chunk;
    const v4f* __restrict__ s0 = (const v4f*)(seg + ((size_t)(b * NC + 2 * g)) * HW + pix);
    const v4f* __restrict__ s1 = (const v4f*)(seg + ((size_t)(b * NC + 2 * g + 1)) * HW + pix);
    const unsigned int* __restrict__ tp = pt + ((size_t)b * HW + pix) / 4;

    const int iters = per_chunk / 4 / TPB;  // 4
    const v4f ones = {1.0f, 1.0f, 1.0f, 1.0f};

    // Software pipeline: next iteration's global loads in flight across LDS RMWs.
    int v = tid;
    unsigned int tw = tp[v];
    v4f a0 = __builtin_nontemporal_load(s0 + v);  // seg is read-once: bypass caches
    v4f a1 = last ? ones : __builtin_nontemporal_load(s1 + v);

    for (int i = 0; i < iters; ++i) {
        unsigned int twn = 0;
        v4f b0 = {}, b1 = {};
        if (i + 1 < iters) {
            const int vn = v + TPB;
            twn = tp[vn];
            b0 = __builtin_nontemporal_load(s0 + vn);
            b1 = last ? ones : __builtin_nontemporal_load(s1 + vn);
        }
        const int t0 = tw & 0xff, t1 = (tw >> 8) & 0xff,
                  t2 = (tw >> 16) & 0xff, t3 = tw >> 24;
        v2f c;
        c = mybins[t0]; c.x += a0.x; c.y += a1.x; mybins[t0] = c;
        c = mybins[t1]; c.x += a0.y; c.y += a1.y; mybins[t1] = c;
        c = mybins[t2]; c.x += a0.z; c.y += a1.z; mybins[t2] = c;
        c = mybins[t3]; c.x += a0.w; c.y += a1.w; mybins[t3] = c;
        tw = twn; a0 = b0; a1 = b1; v += TPB;
    }
    __syncthreads();

    // Fold 256 thread-rows -> 32 rows (v2 domain), flat-parallel, in-place safe.
    v2f* bv = (v2f*)bins;  // [256][NC]
    for (int e = tid; e < 32 * NC; e += TPB) {  // 608 elements
        const int r = e & 31, c2 = e >> 5;
        v2f acc = bv[r * NC + c2];
        #pragma unroll
        for (int j = 1; j < 8; ++j) acc += bv[(r + 32 * j) * NC + c2];
        bv[r * NC + c2] = acc;
    }
    __syncthreads();

    // 19 lanes: sum the 32 rows for class t = tid, flush to global accumulator.
    if (tid < NC) {
        v2f acc = bv[tid];
        #pragma unroll
        for (int r = 1; r < 32; ++r) acc += bv[r * NC + tid];
        float* dst = Sg + ((size_t)b * NC + tid) * 20 + 2 * g;  // cols {2g, 2g+1}; g=9 -> {18, 19=count}
        atomicAdd(dst + 0, acc.x);
        atomicAdd(dst + 1, acc.y);
    }
}

__global__ __launch_bounds__(FT) void finalize_kernel(const float* __restrict__ Sg,
                                                      float* __restrict__ out) {
    __shared__ float S[NB * NC * 20];  // 3040 floats
    __shared__ float wsum[FT / 64];
    const int tid = threadIdx.x;

    for (int e = tid; e < NB * NC * 20; e += FT) S[e] = Sg[e];
    __syncthreads();

    const float eps = 2.220446049250313e-16f;  // np.spacing(1)
    float local = 0.0f;
    for (int idx = tid; idx < NB * NC * NC; idx += FT) {
        const int b = idx / (NC * NC);
        const int r = idx - b * NC * NC;
        const int i = r / NC;
        const int k = r - i * NC;
        const float* Sb = S + b * NC * 20;  // Sb[t*20 + i] = S[b,i,k=t]; Sb[t*20+19] = count
        const float cnt_i = Sb[i * 20 + 19];
        const float cnt_k = Sb[k * 20 + 19];
        const float alpha = (cnt_i > 0.0f) ? Sb[i * 20 + i] / cnt_i : 0.0f;
        const float beta = (cnt_k > 0.0f) ? 1.0f - Sb[k * 20 + i] / cnt_k : 0.0f;
        local += logf(0.5f * (alpha + beta + eps));
    }

    #pragma unroll
    for (int off = 32; off > 0; off >>= 1) local += __shfl_down(local, off);
    if ((tid & 63) == 0) wsum[tid >> 6] = local;
    __syncthreads();
    if (tid == 0) {
        float t = 0.0f;
        #pragma unroll
        for (int w = 0; w < FT / 64; ++w) t += wsum[w];
        out[0] = -0.5f * t / (float)NB;
    }
}

extern "C" void kernel_launch(void* const* d_in, const int* in_sizes, int n_in,
                              void* d_out, int out_size, void* d_ws, size_t ws_size,
                              hipStream_t stream) {
    const float* seg = (const float*)d_in[0];
    const int* tgt = (const int*)d_in[1];

    float* Sg = (float*)d_ws;                       // 12160 B
    int* pt = (int*)((char*)d_ws + 12288);          // packed target, 2 MB

    hipMemsetAsync(Sg, 0, (size_t)NB * NC * 20 * sizeof(float), stream);
    pack_kernel<<<NB * HW / 16 / TPB, TPB, 0, stream>>>(tgt, pt);  // 512 blocks

    dim3 grid(CHUNKS, NG, NB);  // 64 x 10 x 8 = 5120 blocks, 4 resident/CU
    accum_kernel<<<grid, TPB, 0, stream>>>(seg, (const unsigned int*)pt, Sg);
    finalize_kernel<<<1, FT, 0, stream>>>(Sg, (float*)d_out);
}

// Round 6
// 236.101 us; speedup vs baseline: 1.7092x; 1.2289x over previous
//
#include <hip/hip_runtime.h>
#include <math.h>

#define NC 19
#define NB 8
#define HW (512 * 512)
#define CHUNKS 16
#define NG 10   // channel pairs {0,1},...,{16,17}, then {18, counts}
#define TPB 256
#define STRIDE 39  // odd stride in floats: tid*39 covers all 32 banks (gcd(39,32)=1)
#define FT 1024

typedef float v4f __attribute__((ext_vector_type(4)));
typedef int v4i __attribute__((ext_vector_type(4)));

// Workspace: Sg[NB][NC][20] floats (12160 B, zeroed each call; Sg[b][t][i] =
// sum of channel i over class-t pixels, col 19 = class-t count), then packed
// int8 target at byte offset 12288 (2 MB).

__global__ __launch_bounds__(TPB) void pack_kernel(const int* __restrict__ tgt,
                                                   int* __restrict__ pt) {
    // int32 labels (0..18) -> int8. 16 px/thread, fully coalesced.
    const size_t idx = (size_t)blockIdx.x * TPB + threadIdx.x;
    const v4i* tv = (const v4i*)tgt + idx * 4;
    int tmp[4];
    #pragma unroll
    for (int j = 0; j < 4; ++j) {
        v4i t = tv[j];
        tmp[j] = t.x | (t.y << 8) | (t.z << 16) | (t.w << 24);
    }
    v4i o; o.x = tmp[0]; o.y = tmp[1]; o.z = tmp[2]; o.w = tmp[3];
    ((v4i*)pt)[idx] = o;
}

__global__ __launch_bounds__(TPB) void accum_kernel(const float* __restrict__ seg,
                                                    const unsigned int* __restrict__ pt,
                                                    float* __restrict__ Sg) {
    // Per-thread PRIVATE bins, scalar f32, odd stride (R3-proven conflict-free).
    // Two independent RMW chains per thread: p0 = channel c0, p1 = channel c1
    // (or counts in the last group). 39*4 = 156 B/thread -> 39.9 KB -> 4 blk/CU.
    __shared__ float bins[TPB * STRIDE];

    const int tid = threadIdx.x;
    const int chunk = blockIdx.x;
    const int g = blockIdx.y;
    const int b = blockIdx.z;
    const bool last = (g == NG - 1);
    const int c0 = 2 * g;

    float* p0 = &bins[tid * STRIDE];
    float* p1 = p0 + NC;
    #pragma unroll
    for (int k = 0; k < STRIDE; ++k) p0[k] = 0.0f;
    // Rows are thread-private until the fold: no barrier needed here.

    const int per_chunk = HW / CHUNKS;  // 16384 pixels
    const size_t pix = (size_t)chunk * per_chunk;
    const v4f* __restrict__ s0 = (const v4f*)(seg + ((size_t)(b * NC + c0)) * HW + pix);
    const v4f* __restrict__ s1 = (const v4f*)(seg + ((size_t)(b * NC + c0 + 1)) * HW + pix);
    const unsigned int* __restrict__ tp = pt + ((size_t)b * HW + pix) / 4;

    const int iters = per_chunk / 4 / TPB;  // 16
    const v4f ones = {1.0f, 1.0f, 1.0f, 1.0f};

    // Plain (cacheable) loads: harness restores seg into L3 each iteration, so
    // reads can hit Infinity Cache; nt hint would forfeit that (R5 lesson).
    int v = tid;
    unsigned int tw = tp[v];
    v4f a0 = s0[v];
    v4f a1 = last ? ones : s1[v];

    for (int i = 0; i < iters; ++i) {
        unsigned int twn = 0;
        v4f b0 = {}, b1 = ones;
        if (i + 1 < iters) {
            const int vn = v + TPB;
            twn = tp[vn];
            b0 = s0[vn];
            if (!last) b1 = s1[vn];
        }
        const int t0 = tw & 0xff, t1 = (tw >> 8) & 0xff,
                  t2 = (tw >> 16) & 0xff, t3 = tw >> 24;
        // Chain p0 (4 dependent b32 RMWs) and chain p1 run independently.
        p0[t0] += a0.x;  p1[t0] += a1.x;
        p0[t1] += a0.y;  p1[t1] += a1.y;
        p0[t2] += a0.z;  p1[t2] += a1.z;
        p0[t3] += a0.w;  p1[t3] += a1.w;
        tw = twn; a0 = b0; a1 = b1; v += TPB;
    }
    __syncthreads();

    // Stage 1: fold 256 rows -> 32 rows over the 38 live columns, in-place safe.
    for (int e = tid; e < 32 * 2 * NC; e += TPB) {  // 1216 elements
        const int r = e & 31, c = e >> 5;  // c in 0..37
        float acc = bins[r * STRIDE + c];
        #pragma unroll
        for (int j = 1; j < TPB / 32; ++j) acc += bins[(r + 32 * j) * STRIDE + c];
        bins[r * STRIDE + c] = acc;
    }
    __syncthreads();

    // Stage 2: 38 lanes (wave 0) sum the 32 rows of their column, flush global.
    if (tid < 2 * NC) {
        float acc = bins[tid];
        #pragma unroll
        for (int r = 1; r < 32; ++r) acc += bins[r * STRIDE + tid];
        if (tid < NC) {
            // class t = tid, channel c0
            atomicAdd(Sg + ((size_t)b * NC + tid) * 20 + c0, acc);
        } else {
            // class t = tid-19; channel c0+1, or counts col (19) when last (g=9 -> 2g+1=19)
            atomicAdd(Sg + ((size_t)b * NC + (tid - NC)) * 20 + c0 + 1, acc);
        }
    }
}

__global__ __launch_bounds__(FT) void finalize_kernel(const float* __restrict__ Sg,
                                                      float* __restrict__ out) {
    __shared__ float S[NB * NC * 20];  // 3040 floats
    __shared__ float wsum[FT / 64];
    const int tid = threadIdx.x;

    for (int e = tid; e < NB * NC * 20; e += FT) S[e] = Sg[e];
    __syncthreads();

    const float eps = 2.220446049250313e-16f;  // np.spacing(1)
    float local = 0.0f;
    for (int idx = tid; idx < NB * NC * NC; idx += FT) {
        const int b = idx / (NC * NC);
        const int r = idx - b * NC * NC;
        const int i = r / NC;
        const int k = r - i * NC;
        const float* Sb = S + b * NC * 20;  // Sb[t*20 + i] = S[b,i,class t]; [t*20+19] = count
        const float cnt_i = Sb[i * 20 + 19];
        const float cnt_k = Sb[k * 20 + 19];
        const float alpha = (cnt_i > 0.0f) ? Sb[i * 20 + i] / cnt_i : 0.0f;
        const float beta = (cnt_k > 0.0f) ? 1.0f - Sb[k * 20 + i] / cnt_k : 0.0f;
        local += logf(0.5f * (alpha + beta + eps));
    }

    #pragma unroll
    for (int off = 32; off > 0; off >>= 1) local += __shfl_down(local, off);
    if ((tid & 63) == 0) wsum[tid >> 6] = local;
    __syncthreads();
    if (tid == 0) {
        float t = 0.0f;
        #pragma unroll
        for (int w = 0; w < FT / 64; ++w) t += wsum[w];
        out[0] = -0.5f * t / (float)NB;
    }
}

extern "C" void kernel_launch(void* const* d_in, const int* in_sizes, int n_in,
                              void* d_out, int out_size, void* d_ws, size_t ws_size,
                              hipStream_t stream) {
    const float* seg = (const float*)d_in[0];
    const int* tgt = (const int*)d_in[1];

    float* Sg = (float*)d_ws;               // 12160 B
    int* pt = (int*)((char*)d_ws + 12288);  // packed int8 target, 2 MB

    hipMemsetAsync(Sg, 0, (size_t)NB * NC * 20 * sizeof(float), stream);
    pack_kernel<<<NB * HW / 16 / TPB, TPB, 0, stream>>>(tgt, pt);  // 512 blocks

    dim3 grid(CHUNKS, NG, NB);  // 16 x 10 x 8 = 1280 blocks, 16 iters each
    accum_kernel<<<grid, TPB, 0, stream>>>(seg, (const unsigned int*)pt, Sg);
    finalize_kernel<<<1, FT, 0, stream>>>(Sg, (float*)d_out);
}

// Round 7
// 232.439 us; speedup vs baseline: 1.7362x; 1.0158x over previous
//
#include <hip/hip_runtime.h>
#include <math.h>

#define NC 19
#define NB 8
#define HW (512 * 512)
#define CHUNKS 16
#define NG 10      // channel pairs {0,1},...,{16,17}, then {18, counts}
#define TPB 256
#define STRIDE 39  // odd stride in floats: tid*39 covers all 32 banks (gcd(39,32)=1)
#define UNROLL 4   // software-pipeline batch: load 4 iters ahead
#define FT 1024

typedef float v4f __attribute__((ext_vector_type(4)));
typedef int v4i __attribute__((ext_vector_type(4)));

// Workspace: S_part[NB][CHUNKS][NC][20] floats (194,560 B), unique slot per
// (b,chunk,col) -> no zero-init, no atomics. Row t = class, col c in 0..18 =
// sum of channel c over class-t pixels, col 19 = class-t count.

__global__ __launch_bounds__(TPB) void accum_kernel(const float* __restrict__ seg,
                                                    const int* __restrict__ tgt,
                                                    float* __restrict__ S_part) {
    // Per-thread PRIVATE bins, scalar f32, odd stride (conflict-free, R3/R6-proven).
    // 39*4B*256 = 39.9 KB -> 4 blocks/CU resident, 1280 blocks = 5 per CU exactly.
    __shared__ float bins[TPB * STRIDE];

    const int tid = threadIdx.x;
    const int g = blockIdx.x;      // FASTEST: 10 groups sharing one target chunk
    const int chunk = blockIdx.y;  //   are co-dispatched -> target L2/L3 hits
    const int b = blockIdx.z;
    const bool last = (g == NG - 1);
    const int c0 = 2 * g;

    float* p0 = &bins[tid * STRIDE];
    float* p1 = p0 + NC;
    #pragma unroll
    for (int k = 0; k < STRIDE; ++k) p0[k] = 0.0f;
    // Rows are thread-private until the fold: no barrier needed here.

    const int per_chunk = HW / CHUNKS;  // 16384 pixels
    const size_t pix = (size_t)chunk * per_chunk;
    const v4f* __restrict__ s0 = (const v4f*)(seg + ((size_t)(b * NC + c0)) * HW + pix);
    const v4f* __restrict__ s1 = (const v4f*)(seg + ((size_t)(b * NC + c0 + 1)) * HW + pix);
    const v4i* __restrict__ tv = (const v4i*)(tgt + (size_t)b * HW + pix);

    const int iters = per_chunk / 4 / TPB;   // 16
    const int nsuper = iters / UNROLL;       // 4
    const v4f ones = {1.0f, 1.0f, 1.0f, 1.0f};

    // Cacheable loads on purpose: harness restores d_in before every replay, so
    // seg+tgt are L3-warm (R5 evidence: 6.2 MB-FETCH replays). nt would forfeit it.
    v4f A0[UNROLL], A1[UNROLL];
    v4i T[UNROLL];
    #pragma unroll
    for (int j = 0; j < UNROLL; ++j) {
        const int v = j * TPB + tid;
        T[j] = tv[v];
        A0[j] = s0[v];
        A1[j] = last ? ones : s1[v];
    }

    for (int s = 0; s < nsuper; ++s) {
        v4f B0[UNROLL] = {}, B1[UNROLL] = {};
        v4i TN[UNROLL] = {};
        if (s + 1 < nsuper) {
            const int base = (s + 1) * UNROLL * TPB + tid;
            #pragma unroll
            for (int j = 0; j < UNROLL; ++j) {
                const int v = base + j * TPB;
                TN[j] = tv[v];
                B0[j] = s0[v];
                B1[j] = last ? ones : s1[v];
            }
        }
        #pragma unroll
        for (int j = 0; j < UNROLL; ++j) {
            const v4i t = T[j];
            // Two independent 4-deep LDS RMW chains (channel c0 / channel c1-or-count).
            p0[t.x] += A0[j].x;  p1[t.x] += A1[j].x;
            p0[t.y] += A0[j].y;  p1[t.y] += A1[j].y;
            p0[t.z] += A0[j].z;  p1[t.z] += A1[j].z;
            p0[t.w] += A0[j].w;  p1[t.w] += A1[j].w;
        }
        #pragma unroll
        for (int j = 0; j < UNROLL; ++j) { T[j] = TN[j]; A0[j] = B0[j]; A1[j] = B1[j]; }
    }
    __syncthreads();

    // Stage 1: fold 256 rows -> 32 rows over the 38 live columns, in-place safe.
    for (int e = tid; e < 32 * 2 * NC; e += TPB) {  // 1216 elements
        const int r = e & 31, c = e >> 5;  // c in 0..37
        float acc = bins[r * STRIDE + c];
        #pragma unroll
        for (int j = 1; j < TPB / 32; ++j) acc += bins[(r + 32 * j) * STRIDE + c];
        bins[r * STRIDE + c] = acc;
    }
    __syncthreads();

    // Stage 2: 38 lanes (wave 0) sum the 32 rows of their column; plain store
    // to this block's unique slots.
    if (tid < 2 * NC) {
        float acc = bins[tid];
        #pragma unroll
        for (int r = 1; r < 32; ++r) acc += bins[r * STRIDE + tid];
        const int t = (tid < NC) ? tid : tid - NC;        // class
        const int c = (tid < NC) ? c0 : c0 + 1;           // channel col; g=9,hi -> 19 = counts
        S_part[(((size_t)(b * CHUNKS + chunk)) * NC + t) * 20 + c] = acc;
    }
}

__global__ __launch_bounds__(FT) void finalize_kernel(const float* __restrict__ S_part,
                                                      float* __restrict__ out) {
    __shared__ float S[NB * NC * 20];  // 3040 floats: S[b][t][c], col 19 = count
    __shared__ float wsum[FT / 64];
    const int tid = threadIdx.x;

    // Phase A: reduce the 16 chunk partials (coalesced: r is contiguous).
    for (int e = tid; e < NB * NC * 20; e += FT) {
        const int b = e / (NC * 20);
        const int r = e - b * NC * 20;
        float a = 0.0f;
        #pragma unroll
        for (int ch = 0; ch < CHUNKS; ++ch)
            a += S_part[((size_t)(b * CHUNKS + ch)) * (NC * 20) + r];
        S[e] = a;
    }
    __syncthreads();

    // Phase B: 2888 log terms.
    const float eps = 2.220446049250313e-16f;  // np.spacing(1)
    float local = 0.0f;
    for (int idx = tid; idx < NB * NC * NC; idx += FT) {
        const int b = idx / (NC * NC);
        const int r = idx - b * NC * NC;
        const int i = r / NC;
        const int k = r - i * NC;
        const float* Sb = S + b * NC * 20;
        const float cnt_i = Sb[i * 20 + 19];
        const float cnt_k = Sb[k * 20 + 19];
        const float alpha = (cnt_i > 0.0f) ? Sb[i * 20 + i] / cnt_i : 0.0f;
        const float beta = (cnt_k > 0.0f) ? 1.0f - Sb[k * 20 + i] / cnt_k : 0.0f;
        local += logf(0.5f * (alpha + beta + eps));
    }

    #pragma unroll
    for (int off = 32; off > 0; off >>= 1) local += __shfl_down(local, off);
    if ((tid & 63) == 0) wsum[tid >> 6] = local;
    __syncthreads();
    if (tid == 0) {
        float t = 0.0f;
        #pragma unroll
        for (int w = 0; w < FT / 64; ++w) t += wsum[w];
        out[0] = -0.5f * t / (float)NB;
    }
}

extern "C" void kernel_launch(void* const* d_in, const int* in_sizes, int n_in,
                              void* d_out, int out_size, void* d_ws, size_t ws_size,
                              hipStream_t stream) {
    const float* seg = (const float*)d_in[0];
    const int* tgt = (const int*)d_in[1];
    float* S_part = (float*)d_ws;  // 194,560 B; every slot written unconditionally

    dim3 grid(NG, CHUNKS, NB);  // g fastest -> 10 target-sharing blocks co-resident
    accum_kernel<<<grid, TPB, 0, stream>>>(seg, tgt, S_part);
    finalize_kernel<<<1, FT, 0, stream>>>(S_part, (float*)d_out);
}